// Round 1
// baseline (83.761 us; speedup 1.0000x reference)
//
#include <hip/hip_runtime.h>

#define N 2048
#define T 32
#define D 128
#define BT 32
#define MT (N / BT)                 // 64 row-blocks
#define NTILES (MT * (MT + 1) / 2)  // 2080 upper-triangular 32x32 tiles
#define PSTR 33                     // LDS row stride (32 data + 1)

typedef float floatx4 __attribute__((ext_vector_type(4)));
typedef short bf16x8 __attribute__((ext_vector_type(8)));

// s_waitcnt lgkmcnt(0) only — 0xc07f. Single-wave WG: no barrier ever.
#define LGKM0() __builtin_amdgcn_s_waitcnt(0xc07f)

// tile id -> (a,b), a<=b, upper-triangular over MT x MT
__device__ __forceinline__ void tile_decode(int t, int& a, int& b) {
  a = (int)((2 * MT + 1 -
             sqrtf((float)((2 * MT + 1) * (2 * MT + 1) - 8 * t))) * 0.5f);
  while (a > 0 && t < a * MT - a * (a - 1) / 2) --a;
  while (t >= (a + 1) * MT - (a + 1) * a / 2) ++a;
  b = a + (t - (a * MT - a * (a - 1) / 2));
}

// ---------------------------------------------------------------------------
// Kernel 1: normalize each X row, split into truncated-bf16 h/l planes
// (xn = h + l + eps, hh+hl+lh Gram error <= 2^-16 rel — absmax 0.0 in R7),
// and store in MFMA-TILED layout:
//   plane[rb*2048 + ks*512 + q*128 + m*8 + j]  (shorts)
// so a pair-kernel fragment load (lanes = (m,q)) is one fully-coalesced
// 1 KB wave-read. One 64-thread wave per 16-row block; lane (m,q) owns row
// 16rb+m, cols {q*8 + ks*32}.
// ---------------------------------------------------------------------------
__global__ __launch_bounds__(64) void presplit_kernel(
    const float* __restrict__ X, unsigned short* __restrict__ hXt,
    unsigned short* __restrict__ lXt) {
  const int rb   = blockIdx.x;          // 0..127
  const int lane = threadIdx.x;
  const int m    = lane & 15;
  const int q    = lane >> 4;

  const float* xr = X + (size_t)(16 * rb + m) * D + q * 8;
  float4 v0[4], v1[4];
  float ss = 0.0f;
#pragma unroll
  for (int ks = 0; ks < 4; ++ks) {
    v0[ks] = *(const float4*)(xr + ks * 32);
    v1[ks] = *(const float4*)(xr + ks * 32 + 4);
    ss += v0[ks].x * v0[ks].x + v0[ks].y * v0[ks].y +
          v0[ks].z * v0[ks].z + v0[ks].w * v0[ks].w +
          v1[ks].x * v1[ks].x + v1[ks].y * v1[ks].y +
          v1[ks].z * v1[ks].z + v1[ks].w * v1[ks].w;
  }
  // row sumsq: lanes m, m+16, m+32, m+48 hold the 4 col-quads of row m
  ss += __shfl_xor(ss, 16, 64);
  ss += __shfl_xor(ss, 32, 64);
  const float rn = rsqrtf(ss);

#pragma unroll
  for (int ks = 0; ks < 4; ++ks) {
    bf16x8 h, l;
    float v[8] = {v0[ks].x, v0[ks].y, v0[ks].z, v0[ks].w,
                  v1[ks].x, v1[ks].y, v1[ks].z, v1[ks].w};
#pragma unroll
    for (int i = 0; i < 8; ++i) {
      const float a = v[i] * rn;
      const unsigned u = __float_as_uint(a);
      h[i] = (short)(u >> 16);
      const float lo = a - __uint_as_float(u & 0xffff0000u);  // exact
      l[i] = (short)(__float_as_uint(lo) >> 16);
    }
    const size_t o = (size_t)rb * 2048 + ks * 512 + q * 128 + m * 8;
    *(bf16x8*)(hXt + o) = h;
    *(bf16x8*)(lXt + o) = l;
  }
}

// ---------------------------------------------------------------------------
// Kernel 2: one FULL 32x32 tile per single-wave block (R10: was 16x32 halves).
// Per tile vs the half-tile scheme: pred staging 96->64 rows, fragment loads
// 48->32 (B fragments reused across both A 16-row blocks), tile_decode /
// epilogue / partial-store x1 instead of x2. MFMA + hinge totals unchanged.
// Per-block partials to distinct addresses (no atomics — R8's regression).
// ---------------------------------------------------------------------------
__global__ __launch_bounds__(64) void pair_kernel(
    const float* __restrict__ pred,          // [N][T]
    const unsigned short* __restrict__ hXt,  // tiled bf16 high plane
    const unsigned short* __restrict__ lXt,  // tiled bf16 low plane
    const float* __restrict__ scale_p,       // [1]
    double* __restrict__ partials) {         // [NTILES]
  __shared__ float P[64 * PSTR];             // 32 A-pred rows + 32 B-pred rows

  const int lane = threadIdx.x;
  const int tile = blockIdx.x;

  int a, b;
  tile_decode(tile, a, b);
  const int aRow0 = a * BT, bRow0 = b * BT;
  const int m    = lane & 15;
  const int quad = lane >> 4;
  const float scale = scale_p[0];

  // ---- stage 64 pred rows: 512 float4 chunks / 64 lanes = 8 each
#pragma unroll
  for (int s = 0; s < 8; ++s) {
    const int idx = s * 64 + lane;
    const int row = idx >> 3;
    const int fo  = (idx & 7) * 4;
    const int grow = (row < 32) ? (aRow0 + row) : (bRow0 + row - 32);
    *(float4*)(&P[row * PSTR + fo]) =
        *(const float4*)(pred + (size_t)grow * T + fo);
  }

  // ---- Gram full tile via split-bf16 MFMA, tiled coalesced fragment loads
  floatx4 accf[2][2];
#pragma unroll
  for (int i = 0; i < 2; ++i)
#pragma unroll
    for (int J = 0; J < 2; ++J)
      accf[i][J] = (floatx4){0.f, 0.f, 0.f, 0.f};

  const int arb = a * 2;                     // A 16-row blocks: arb, arb+1
  const int brb = b * 2;                     // B 16-row blocks: brb, brb+1
  const size_t fo2 = (size_t)quad * 128 + m * 8;
  const unsigned short* ph = hXt + fo2;
  const unsigned short* pl = lXt + fo2;

#pragma unroll
  for (int ks = 0; ks < 4; ++ks) {
    bf16x8 hA[2], lA[2], hB[2], lB[2];
#pragma unroll
    for (int i = 0; i < 2; ++i) {
      hA[i] = *(const bf16x8*)(ph + (size_t)(arb + i) * 2048 + ks * 512);
      lA[i] = *(const bf16x8*)(pl + (size_t)(arb + i) * 2048 + ks * 512);
      hB[i] = *(const bf16x8*)(ph + (size_t)(brb + i) * 2048 + ks * 512);
      lB[i] = *(const bf16x8*)(pl + (size_t)(brb + i) * 2048 + ks * 512);
    }
#pragma unroll
    for (int i = 0; i < 2; ++i)
#pragma unroll
      for (int J = 0; J < 2; ++J) {
        accf[i][J] =
            __builtin_amdgcn_mfma_f32_16x16x32_bf16(hA[i], hB[J], accf[i][J], 0, 0, 0);
        accf[i][J] =
            __builtin_amdgcn_mfma_f32_16x16x32_bf16(hA[i], lB[J], accf[i][J], 0, 0, 0);
        accf[i][J] =
            __builtin_amdgcn_mfma_f32_16x16x32_bf16(lA[i], hB[J], accf[i][J], 0, 0, 0);
      }
  }

  // ---- sd = scale*(1 - G); C layout: row = quad*4+r (A), col = 16J+m (B)
  float sd[2][2][4], ps[2][2][4];
#pragma unroll
  for (int i = 0; i < 2; ++i)
#pragma unroll
    for (int J = 0; J < 2; ++J)
#pragma unroll
      for (int r = 0; r < 4; ++r) {
        sd[i][J][r] = scale * (1.0f - accf[i][J][r]);
        ps[i][J][r] = 0.0f;
      }
  LGKM0();  // pred staging visible (single wave: DS in-order)

  // ---- hinge: sum_t max(|dp|, s); -32s correction under the mask
#pragma unroll
  for (int t4 = 0; t4 < 8; ++t4) {
    float4 qb[2];
    qb[0] = *(const float4*)(&P[(32 + m) * PSTR + t4 * 4]);
    qb[1] = *(const float4*)(&P[(48 + m) * PSTR + t4 * 4]);
#pragma unroll
    for (int i = 0; i < 2; ++i)
#pragma unroll
      for (int r = 0; r < 4; ++r) {
        float4 qa = *(const float4*)(&P[(i * 16 + quad * 4 + r) * PSTR + t4 * 4]);
#pragma unroll
        for (int J = 0; J < 2; ++J) {
          float s = sd[i][J][r];
          ps[i][J][r] += fmaxf(fabsf(qa.x - qb[J].x), s) +
                         fmaxf(fabsf(qa.y - qb[J].y), s) +
                         fmaxf(fabsf(qa.z - qb[J].z), s) +
                         fmaxf(fabsf(qa.w - qb[J].w), s);
        }
      }
  }

  // ---- mask + correction + wave reduction
  float tsum = 0.0f;
#pragma unroll
  for (int i = 0; i < 2; ++i)
#pragma unroll
    for (int J = 0; J < 2; ++J)
#pragma unroll
      for (int r = 0; r < 4; ++r) {
        const int ja   = aRow0 + i * 16 + quad * 4 + r;
        const int kcol = bRow0 + 16 * J + m;
        tsum += (kcol > ja) ? (ps[i][J][r] - 32.0f * sd[i][J][r]) : 0.0f;
      }

  double dsum = (double)tsum;
#pragma unroll
  for (int off = 32; off > 0; off >>= 1) dsum += __shfl_down(dsum, off, 64);
  if (lane == 0) partials[tile] = dsum;
}

// ---------------------------------------------------------------------------
// Kernel 3: sum NTILES partials, scale, clamp.
// ---------------------------------------------------------------------------
__global__ __launch_bounds__(256) void finalize_kernel(
    const double* __restrict__ partials, const float* __restrict__ target,
    float* __restrict__ out) {
  __shared__ double red[4];
  double s = 0.0;
  for (int i = threadIdx.x; i < NTILES; i += 256) s += partials[i];
#pragma unroll
  for (int off = 32; off > 0; off >>= 1) s += __shfl_down(s, off, 64);
  int wave = threadIdx.x >> 6, lane = threadIdx.x & 63;
  if (lane == 0) red[wave] = s;
  __syncthreads();
  if (threadIdx.x == 0) {
    double tot = red[0] + red[1] + red[2] + red[3];
    double mf  = 2.0 * tot / ((double)N * (double)(N - 1) * (double)T);
    double r   = mf - (double)target[0];
    out[0] = (float)(r > 0.0 ? r : 0.0);
  }
}

extern "C" void kernel_launch(void* const* d_in, const int* in_sizes, int n_in,
                              void* d_out, int out_size, void* d_ws, size_t ws_size,
                              hipStream_t stream) {
  const float* target = (const float*)d_in[0];
  const float* pred   = (const float*)d_in[1];
  const float* X      = (const float*)d_in[2];
  // d_in[3] = ntimes (==32, hardcoded); d_in[4] = scale
  const float* scale  = (const float*)d_in[4];

  double*         partials = (double*)d_ws;                          // 16.6 KB
  unsigned short* hXt = (unsigned short*)((char*)d_ws + (1u << 20)); // 512 KB
  unsigned short* lXt = (unsigned short*)((char*)d_ws + (2u << 20)); // 512 KB

  presplit_kernel<<<dim3(D), dim3(64), 0, stream>>>(X, hXt, lXt);
  pair_kernel<<<dim3(NTILES), dim3(64), 0, stream>>>(pred, hXt, lXt, scale,
                                                     partials);
  finalize_kernel<<<dim3(1), dim3(256), 0, stream>>>(partials, target,
                                                     (float*)d_out);
}

// Round 2
// 82.100 us; speedup vs baseline: 1.0202x; 1.0202x over previous
//
#include <hip/hip_runtime.h>

#define N 2048
#define T 32
#define D 128
#define BT 32
#define MT (N / BT)                 // 64 row-blocks
#define NTILES (MT * (MT + 1) / 2)  // 2080 upper-triangular 32x32 tiles
#define NHALF (2 * NTILES)          // 4160 16x32 half-tiles (one per WG)
#define NWAVES (2 * NHALF)          // 8320 16x16 quarter-tile waves
#define PSTR 33                     // LDS row stride (32 data + 1)

typedef float floatx4 __attribute__((ext_vector_type(4)));
typedef short bf16x8 __attribute__((ext_vector_type(8)));

// tile id -> (a,b), a<=b, upper-triangular over MT x MT
__device__ __forceinline__ void tile_decode(int t, int& a, int& b) {
  a = (int)((2 * MT + 1 -
             sqrtf((float)((2 * MT + 1) * (2 * MT + 1) - 8 * t))) * 0.5f);
  while (a > 0 && t < a * MT - a * (a - 1) / 2) --a;
  while (t >= (a + 1) * MT - (a + 1) * a / 2) ++a;
  b = a + (t - (a * MT - a * (a - 1) / 2));
}

// ---------------------------------------------------------------------------
// Kernel 1: normalize each X row, split into truncated-bf16 h/l planes
// (xn = h + l + eps, hh+hl+lh Gram error <= 2^-16 rel — absmax 0.0 in R7),
// and store in MFMA-TILED layout:
//   plane[rb*2048 + ks*512 + q*128 + m*8 + j]  (shorts)
// so a pair-kernel fragment load (lanes = (m,q)) is one fully-coalesced
// 1 KB wave-read. One 64-thread wave per 16-row block; lane (m,q) owns row
// 16rb+m, cols {q*8 + ks*32}.
// ---------------------------------------------------------------------------
__global__ __launch_bounds__(64) void presplit_kernel(
    const float* __restrict__ X, unsigned short* __restrict__ hXt,
    unsigned short* __restrict__ lXt) {
  const int rb   = blockIdx.x;          // 0..127
  const int lane = threadIdx.x;
  const int m    = lane & 15;
  const int q    = lane >> 4;

  const float* xr = X + (size_t)(16 * rb + m) * D + q * 8;
  float4 v0[4], v1[4];
  float ss = 0.0f;
#pragma unroll
  for (int ks = 0; ks < 4; ++ks) {
    v0[ks] = *(const float4*)(xr + ks * 32);
    v1[ks] = *(const float4*)(xr + ks * 32 + 4);
    ss += v0[ks].x * v0[ks].x + v0[ks].y * v0[ks].y +
          v0[ks].z * v0[ks].z + v0[ks].w * v0[ks].w +
          v1[ks].x * v1[ks].x + v1[ks].y * v1[ks].y +
          v1[ks].z * v1[ks].z + v1[ks].w * v1[ks].w;
  }
  // row sumsq: lanes m, m+16, m+32, m+48 hold the 4 col-quads of row m
  ss += __shfl_xor(ss, 16, 64);
  ss += __shfl_xor(ss, 32, 64);
  const float rn = rsqrtf(ss);

#pragma unroll
  for (int ks = 0; ks < 4; ++ks) {
    bf16x8 h, l;
    float v[8] = {v0[ks].x, v0[ks].y, v0[ks].z, v0[ks].w,
                  v1[ks].x, v1[ks].y, v1[ks].z, v1[ks].w};
#pragma unroll
    for (int i = 0; i < 8; ++i) {
      const float a = v[i] * rn;
      const unsigned u = __float_as_uint(a);
      h[i] = (short)(u >> 16);
      const float lo = a - __uint_as_float(u & 0xffff0000u);  // exact
      l[i] = (short)(__float_as_uint(lo) >> 16);
    }
    const size_t o = (size_t)rb * 2048 + ks * 512 + q * 128 + m * 8;
    *(bf16x8*)(hXt + o) = h;
    *(bf16x8*)(lXt + o) = l;
  }
}

// ---------------------------------------------------------------------------
// Kernel 2 (R11): one 16x16 QUARTER-tile per wave, 2 waves per 128-thread WG
// sharing one staged 48-row pred panel (16 A rows + 32 B rows) in LDS.
// vs R9 half-tile waves: 2x the waves (8320 -> ~8/SIMD grid average), half
// the per-wave hinge VALU / Gram state / VGPR. Total MFMA+VALU+LDS work
// unchanged; decomposition finer to attack the latency/occupancy limit
// R10's regression exposed. Per-wave partials, no atomics (R8 regression).
// ---------------------------------------------------------------------------
__global__ __launch_bounds__(128) void pair_kernel(
    const float* __restrict__ pred,          // [N][T]
    const unsigned short* __restrict__ hXt,  // tiled bf16 high plane
    const unsigned short* __restrict__ lXt,  // tiled bf16 low plane
    const float* __restrict__ scale_p,       // [1]
    double* __restrict__ partials) {         // [NWAVES]
  __shared__ float P[48 * PSTR];             // 16 A-pred rows + 32 B-pred rows

  const int tid  = threadIdx.x;
  const int lane = tid & 63;
  const int J    = tid >> 6;                 // wave id = B 16-col half
  const int w    = blockIdx.x;               // half-tile id
  const int tile = w >> 1;
  const int h    = w & 1;                    // A-row half: rows 16h..16h+15

  int a, b;
  tile_decode(tile, a, b);
  const int aRow0 = a * BT, bRow0 = b * BT;
  const int m    = lane & 15;
  const int quad = lane >> 4;
  const float scale = scale_p[0];

  // ---- stage 48 pred rows: 384 float4 chunks / 128 threads = 3 each
#pragma unroll
  for (int s = 0; s < 3; ++s) {
    const int idx = s * 128 + tid;
    const int row = idx >> 3;
    const int fo  = (idx & 7) * 4;
    const int grow = (row < 16) ? (aRow0 + 16 * h + row) : (bRow0 + row - 16);
    *(float4*)(&P[row * PSTR + fo]) =
        *(const float4*)(pred + (size_t)grow * T + fo);
  }

  // ---- Gram quarter-tile via split-bf16 MFMA, coalesced fragment loads
  floatx4 accf = (floatx4){0.f, 0.f, 0.f, 0.f};

  const int arb = a * 2 + h;                 // A 16-row block
  const int brb = b * 2 + J;                 // this wave's B 16-row block
  const size_t fo2 = (size_t)quad * 128 + m * 8;
  const unsigned short* pa_h = hXt + (size_t)arb * 2048 + fo2;
  const unsigned short* pa_l = lXt + (size_t)arb * 2048 + fo2;
  const unsigned short* pb_h = hXt + (size_t)brb * 2048 + fo2;
  const unsigned short* pb_l = lXt + (size_t)brb * 2048 + fo2;

#pragma unroll
  for (int ks = 0; ks < 4; ++ks) {
    bf16x8 hA = *(const bf16x8*)(pa_h + ks * 512);
    bf16x8 lA = *(const bf16x8*)(pa_l + ks * 512);
    bf16x8 hB = *(const bf16x8*)(pb_h + ks * 512);
    bf16x8 lB = *(const bf16x8*)(pb_l + ks * 512);
    accf = __builtin_amdgcn_mfma_f32_16x16x32_bf16(hA, hB, accf, 0, 0, 0);
    accf = __builtin_amdgcn_mfma_f32_16x16x32_bf16(hA, lB, accf, 0, 0, 0);
    accf = __builtin_amdgcn_mfma_f32_16x16x32_bf16(lA, hB, accf, 0, 0, 0);
  }

  // ---- sd = scale*(1 - G); C layout: row = quad*4+r (A), col = m (B)
  float sd[4], ps[4];
#pragma unroll
  for (int r = 0; r < 4; ++r) {
    sd[r] = scale * (1.0f - accf[r]);
    ps[r] = 0.0f;
  }

  __syncthreads();  // staged pred panel visible to both waves

  // ---- hinge: sum_t max(|dp|, s); -32s correction under the mask
#pragma unroll
  for (int t4 = 0; t4 < 8; ++t4) {
    const float4 qb = *(const float4*)(&P[(16 + 16 * J + m) * PSTR + t4 * 4]);
#pragma unroll
    for (int r = 0; r < 4; ++r) {
      const float4 qa = *(const float4*)(&P[(quad * 4 + r) * PSTR + t4 * 4]);
      const float s = sd[r];
      ps[r] += fmaxf(fabsf(qa.x - qb.x), s) +
               fmaxf(fabsf(qa.y - qb.y), s) +
               fmaxf(fabsf(qa.z - qb.z), s) +
               fmaxf(fabsf(qa.w - qb.w), s);
    }
  }

  // ---- mask + correction + wave reduction
  float tsum = 0.0f;
#pragma unroll
  for (int r = 0; r < 4; ++r) {
    const int ja   = aRow0 + 16 * h + quad * 4 + r;
    const int kcol = bRow0 + 16 * J + m;
    tsum += (kcol > ja) ? (ps[r] - 32.0f * sd[r]) : 0.0f;
  }

  double dsum = (double)tsum;
#pragma unroll
  for (int off = 32; off > 0; off >>= 1) dsum += __shfl_down(dsum, off, 64);
  if (lane == 0) partials[2 * w + J] = dsum;
}

// ---------------------------------------------------------------------------
// Kernel 3: sum NWAVES partials, scale, clamp.
// ---------------------------------------------------------------------------
__global__ __launch_bounds__(256) void finalize_kernel(
    const double* __restrict__ partials, const float* __restrict__ target,
    float* __restrict__ out) {
  __shared__ double red[4];
  double s = 0.0;
  for (int i = threadIdx.x; i < NWAVES; i += 256) s += partials[i];
#pragma unroll
  for (int off = 32; off > 0; off >>= 1) s += __shfl_down(s, off, 64);
  int wave = threadIdx.x >> 6, lane = threadIdx.x & 63;
  if (lane == 0) red[wave] = s;
  __syncthreads();
  if (threadIdx.x == 0) {
    double tot = red[0] + red[1] + red[2] + red[3];
    double mf  = 2.0 * tot / ((double)N * (double)(N - 1) * (double)T);
    double r   = mf - (double)target[0];
    out[0] = (float)(r > 0.0 ? r : 0.0);
  }
}

extern "C" void kernel_launch(void* const* d_in, const int* in_sizes, int n_in,
                              void* d_out, int out_size, void* d_ws, size_t ws_size,
                              hipStream_t stream) {
  const float* target = (const float*)d_in[0];
  const float* pred   = (const float*)d_in[1];
  const float* X      = (const float*)d_in[2];
  // d_in[3] = ntimes (==32, hardcoded); d_in[4] = scale
  const float* scale  = (const float*)d_in[4];

  double*         partials = (double*)d_ws;                          // 66.6 KB
  unsigned short* hXt = (unsigned short*)((char*)d_ws + (1u << 20)); // 512 KB
  unsigned short* lXt = (unsigned short*)((char*)d_ws + (2u << 20)); // 512 KB

  presplit_kernel<<<dim3(D), dim3(64), 0, stream>>>(X, hXt, lXt);
  pair_kernel<<<dim3(NHALF), dim3(128), 0, stream>>>(pred, hXt, lXt, scale,
                                                     partials);
  finalize_kernel<<<dim3(1), dim3(256), 0, stream>>>(partials, target,
                                                     (float*)d_out);
}